// Round 9
// baseline (643.913 us; speedup 1.0000x reference)
//
#include <hip/hip_runtime.h>
#include <hip/hip_bf16.h>
#include <math.h>

#define B_   16
#define S_   4096
#define D_   768
#define H_   384
#define NTOK (B_ * S_)
#define KTOP 40
#define NCAND 128          // filter keeps top-128 per batch; true top-40 margin ~100x
#define NTILES 24          // 384/16 n-tiles
#define KCH    24          // 768/32 k-chunks

typedef __attribute__((ext_vector_type(8))) short bf16x8;
typedef __attribute__((ext_vector_type(4))) float f32x4;

static __device__ __forceinline__ unsigned short f2bf(float x) {
    __hip_bfloat16 h = __float2bfloat16(x);   // HW RNE convert
    unsigned short r;
    __builtin_memcpy(&r, &h, sizeof(r));
    return r;
}
static __device__ __forceinline__ float bf2f(unsigned short h) {
    union { unsigned u; float f; } v; v.u = ((unsigned)h) << 16; return v.f;
}

// Raw workgroup barrier WITHOUT the vmcnt(0) drain __syncthreads() emits.
#define KBARRIER()                                                \
    do {                                                          \
        asm volatile("s_waitcnt lgkmcnt(0)" ::: "memory");        \
        __builtin_amdgcn_s_barrier();                             \
        asm volatile("" ::: "memory");                            \
    } while (0)

// ---------------------------------------------------------------------------
// Kernel 0: pack W1 (fp32 [768][384]) into CHUNK-MAJOR MFMA B layout, bf16
// hi/lo. Fragment element j of lane:
//   B[k = ch*32 + (lane>>4)*8 + j][n = nt*16 + (lane&15)]
//   dst = ((ch*NTILES + nt)*64 + lane)*8
// Chunk-major: all n-tiles of one k-chunk are a contiguous 24 KB slice, so
// every wave at chunk c streams the same L1/L2-hot region.
// ---------------------------------------------------------------------------
__global__ __launch_bounds__(64) void pack_w1(const float* __restrict__ W1,
                                              unsigned short* __restrict__ bh,
                                              unsigned short* __restrict__ bl)
{
    const int nt   = blockIdx.x;        // 0..23
    const int ch   = blockIdx.y;        // 0..23
    const int lane = threadIdx.x;
    const int n    = nt * 16 + (lane & 15);
    const int k0   = ch * 32 + (lane >> 4) * 8;

    const size_t dst = ((size_t)(ch * NTILES + nt) * 64 + lane) * 8;
#pragma unroll
    for (int j = 0; j < 8; ++j) {
        const float v = W1[(size_t)(k0 + j) * H_ + n];
        const unsigned short h = f2bf(v);
        bh[dst + j] = h;
        bl[dst + j] = f2bf(v - bf2f(h));
    }
}

// ---------------------------------------------------------------------------
// Kernel 1: APPROXIMATE filter scores — BARRIER-FREE. Evidence: v0->v7 shows
// the staged structure is latency-bound (all pipes <20%), immune to work
// cuts. Here each wave owns 16 rows x 384 cols independently:
//  - A fragment = 8 consecutive fp32 of the lane's OWN row (row=lane&15,
//    k=(lane>>4)*8): loaded per-lane direct from global, zero redundancy,
//    NO LDS, NO barriers anywhere in the kernel.
//  - acc[24] f32x4 = 96 VGPR; 24 independent MFMA chains/chunk -> deep ILP.
//  - B chunk-major: per-chunk 24KB slice shared by all waves (L1/L2 hot).
//  - Epilogue wave-local via shfl_xor over the 16-lane col groups.
// Block = 256 (4 independent waves = 64 rows), grid 1024.
// ---------------------------------------------------------------------------
__global__ __launch_bounds__(256, 3) void score_kernel(
    const float* __restrict__ features,
    const unsigned short* __restrict__ bh_g,
    const float* __restrict__ b1,
    const float* __restrict__ gamma,
    const float* __restrict__ beta,
    const float* __restrict__ W2,
    const float* __restrict__ b2,
    float* __restrict__ scores)
{
    const int tid  = threadIdx.x;
    const int lane = tid & 63;
    const int w    = tid >> 6;
    const int cl   = lane & 15;
    const int p    = lane >> 4;
    const int rowbase = blockIdx.x * 64 + w * 16;

    f32x4 acc[24];
#pragma unroll
    for (int t = 0; t < 24; ++t) acc[t] = (f32x4){0.f, 0.f, 0.f, 0.f};

    // lane's own A-fragment source: row rowbase+cl, cols p*8 .. p*8+7
    const float* arow = features + (size_t)(rowbase + cl) * D_ + p * 8;

    float4 a0 = *(const float4*)(arow);
    float4 a1 = *(const float4*)(arow + 4);

    for (int c = 0; c < KCH; ++c) {
        // prefetch next chunk's fragment (in flight under this chunk's MFMAs)
        float4 n0, n1;
        if (c + 1 < KCH) {
            n0 = *(const float4*)(arow + (c + 1) * 32);
            n1 = *(const float4*)(arow + (c + 1) * 32 + 4);
        }
        // convert current fragment in registers
        bf16x8 ah;
        ah[0] = (short)f2bf(a0.x); ah[1] = (short)f2bf(a0.y);
        ah[2] = (short)f2bf(a0.z); ah[3] = (short)f2bf(a0.w);
        ah[4] = (short)f2bf(a1.x); ah[5] = (short)f2bf(a1.y);
        ah[6] = (short)f2bf(a1.z); ah[7] = (short)f2bf(a1.w);

        // 24 independent MFMA chains; B slice for chunk c is contiguous 24KB
        const unsigned short* bb = bh_g + (size_t)c * (NTILES * 64 * 8) + lane * 8;
#pragma unroll
        for (int t = 0; t < 24; ++t) {
            const bf16x8 bf = *(const bf16x8*)(bb + t * (64 * 8));
            acc[t] = __builtin_amdgcn_mfma_f32_16x16x32_bf16(ah, bf, acc[t], 0, 0, 0);
        }
        if (c + 1 < KCH) { a0 = n0; a1 = n1; }
    }

    // ---- wave-local epilogue (no LDS): rows p*4+r, cols t*16+cl ----
    // h = acc + b1
#pragma unroll
    for (int t = 0; t < 24; ++t) {
        const float bv = b1[t * 16 + cl];
#pragma unroll
        for (int r = 0; r < 4; ++r) acc[t][r] += bv;
    }
    // mean
    float mu[4];
    {
        float sm[4] = {0.f, 0.f, 0.f, 0.f};
#pragma unroll
        for (int t = 0; t < 24; ++t)
#pragma unroll
            for (int r = 0; r < 4; ++r) sm[r] += acc[t][r];
#pragma unroll
        for (int r = 0; r < 4; ++r) {
#pragma unroll
            for (int off = 1; off <= 8; off <<= 1) sm[r] += __shfl_xor(sm[r], off, 64);
            mu[r] = sm[r] * (1.0f / H_);
        }
    }
    // variance
    float rs[4];
    {
        float sv[4] = {0.f, 0.f, 0.f, 0.f};
#pragma unroll
        for (int t = 0; t < 24; ++t)
#pragma unroll
            for (int r = 0; r < 4; ++r) { const float d = acc[t][r] - mu[r]; sv[r] += d * d; }
#pragma unroll
        for (int r = 0; r < 4; ++r) {
#pragma unroll
            for (int off = 1; off <= 8; off <<= 1) sv[r] += __shfl_xor(sv[r], off, 64);
            rs[r] = rsqrtf(sv[r] * (1.0f / H_) + 1e-5f);
        }
    }
    // LN + gelu + W2 dot
    {
        float ss[4] = {0.f, 0.f, 0.f, 0.f};
#pragma unroll
        for (int t = 0; t < 24; ++t) {
            const int n = t * 16 + cl;
            const float gv = gamma[n], bev = beta[n], wv = W2[n];
#pragma unroll
            for (int r = 0; r < 4; ++r) {
                const float y  = (acc[t][r] - mu[r]) * rs[r] * gv + bev;
                const float ge = 0.5f * y * (1.0f + erff(y * 0.70710678118654752f));
                ss[r] = fmaf(ge, wv, ss[r]);
            }
        }
#pragma unroll
        for (int r = 0; r < 4; ++r) {
#pragma unroll
            for (int off = 1; off <= 8; off <<= 1) ss[r] += __shfl_xor(ss[r], off, 64);
        }
        if (cl == 0) {
#pragma unroll
            for (int r = 0; r < 4; ++r)
                scores[rowbase + p * 4 + r] = 1.0f / (1.0f + expf(-(ss[r] + b2[0])));
        }
    }
}

// ---------------------------------------------------------------------------
// Kernel 2: per-batch top-NCAND(128) candidates via byte-wise radix select on
// approx score bits (scores > 0 so uint order == float order). Ties -> lower
// index. Output order irrelevant: final kernel re-sorts by exact score.
// ---------------------------------------------------------------------------
__global__ __launch_bounds__(256) void cand_kernel(const float* __restrict__ scores,
                                                   int* __restrict__ cand)
{
    __shared__ unsigned int bits_s[S_];     // 16 KB
    __shared__ unsigned int hist[256];
    __shared__ unsigned int suf[256];
    __shared__ unsigned int wtot[4];
    __shared__ int s_byte, s_rem;
    __shared__ unsigned int s_ngt, s_neq;
    __shared__ unsigned int candV[NCAND];
    __shared__ int candI[NCAND];
    __shared__ int eqI[256];

    const int b    = blockIdx.x;
    const int tid  = threadIdx.x;
    const int lane = tid & 63;
    const int w4   = tid >> 6;

    for (int i = tid; i < S_; i += 256)
        bits_s[i] = __float_as_uint(scores[b * S_ + i]);
    if (tid == 0) { s_rem = NCAND; s_ngt = 0u; s_neq = 0u; }

    unsigned int prefix = 0u, mask = 0u;
    for (int pb = 3; pb >= 0; --pb) {
        hist[tid] = 0u;
        __syncthreads();
        for (int i = tid; i < S_; i += 256) {
            const unsigned int u = bits_s[i];
            if ((u & mask) == prefix) atomicAdd(&hist[(u >> (8 * pb)) & 255u], 1u);
        }
        __syncthreads();
        {
            unsigned int v = hist[tid];
#pragma unroll
            for (int off = 1; off < 64; off <<= 1) {
                const unsigned int y = __shfl_down(v, off, 64);
                if (lane + off < 64) v += y;
            }
            if (lane == 0) wtot[w4] = v;
            __syncthreads();
            unsigned int add = 0u;
#pragma unroll
            for (int j = 0; j < 4; ++j) if (j > w4) add += wtot[j];
            v += add;
            suf[tid] = v;
            __syncthreads();
            const int rem = s_rem;
            const unsigned int nxt = (tid < 255) ? suf[tid + 1] : 0u;
            if (suf[tid] >= (unsigned)rem && (tid == 255 || nxt < (unsigned)rem)) {
                s_byte = tid;
                s_rem  = rem - (int)nxt;
            }
        }
        __syncthreads();
        prefix |= ((unsigned int)s_byte) << (8 * pb);
        mask   |= 0xFFu << (8 * pb);
        __syncthreads();
    }
    const unsigned int T = prefix;
    const int need = s_rem;                 // 1..: #ties at T to keep

    for (int i = tid; i < S_; i += 256) {
        const unsigned int u = bits_s[i];
        if (u > T) {
            const unsigned int pos = atomicAdd(&s_ngt, 1u);
            candV[pos] = u; candI[pos] = i;          // n_gt <= NCAND-1 guaranteed
        } else if (u == T) {
            const unsigned int pos = atomicAdd(&s_neq, 1u);
            if (pos < 256u) eqI[pos] = i;
        }
    }
    __syncthreads();
    const int ngt = (int)s_ngt;
    const int neq = (int)(s_neq < 256u ? s_neq : 256u);
    for (int j = tid; j < neq; j += 256) {
        int rank = 0;
        for (int l = 0; l < neq; ++l) rank += (eqI[l] < eqI[j]) ? 1 : 0;
        if (rank < need) { candV[ngt + rank] = T; candI[ngt + rank] = eqI[j]; }
    }
    __syncthreads();
    if (tid < NCAND) cand[b * NCAND + tid] = candI[tid];
}

// ---------------------------------------------------------------------------
// Kernel 3: EXACT rescore = the proven v6 3-term bf16-split MFMA kernel
// applied to 32 candidates per block (grid 4 x 16, ~64 blocks). Per-token
// arithmetic and accumulation order are IDENTICAL to v6 (absmax 0, twice),
// so rescored values match v6's full-scan scores bitwise.
// ---------------------------------------------------------------------------
__global__ __launch_bounds__(256, 4) void rescore_kernel(
    const float* __restrict__ features,
    const unsigned short* __restrict__ bh_g,
    const unsigned short* __restrict__ bl_g,
    const float* __restrict__ b1,
    const float* __restrict__ gamma,
    const float* __restrict__ beta,
    const float* __restrict__ W2,
    const float* __restrict__ b2,
    const int* __restrict__ cand,
    float* __restrict__ escore)
{
    __shared__ unsigned short Ah[32][40];
    __shared__ unsigned short Al[32][40];
    __shared__ float red[4][32];
    __shared__ float mu_s[32];
    __shared__ float rs_s[32];

    const int tid  = threadIdx.x;
    const int lane = tid & 63;
    const int w    = tid >> 6;
    const int g    = blockIdx.x;            // candidate group 0..3
    const int b    = blockIdx.y;            // batch 0..15
    const int cl   = lane & 15;
    const int p    = lane >> 4;

    f32x4 acc[2][6];
#pragma unroll
    for (int m = 0; m < 2; ++m)
#pragma unroll
        for (int t = 0; t < 6; ++t) acc[m][t] = (f32x4){0.f, 0.f, 0.f, 0.f};

    // staging map: thread covers one float4 of its candidate row
    const int r0 = tid >> 3, c0 = (tid & 7) * 4;
    const int ci = cand[b * NCAND + g * 32 + r0];
    const float* arow = features + ((size_t)b * S_ + ci) * D_ + c0;

    float4 p0 = *(const float4*)(arow);

    for (int c = 0; c < KCH; ++c) {
        if (c) KBARRIER();
        {
            unsigned short h0 = f2bf(p0.x), h1 = f2bf(p0.y), h2 = f2bf(p0.z), h3 = f2bf(p0.w);
            Ah[r0][c0] = h0; Ah[r0][c0+1] = h1; Ah[r0][c0+2] = h2; Ah[r0][c0+3] = h3;
            Al[r0][c0]   = f2bf(p0.x - bf2f(h0));
            Al[r0][c0+1] = f2bf(p0.y - bf2f(h1));
            Al[r0][c0+2] = f2bf(p0.z - bf2f(h2));
            Al[r0][c0+3] = f2bf(p0.w - bf2f(h3));
        }
        KBARRIER();

        if (c + 1 < KCH) p0 = *(const float4*)(arow + (c + 1) * 32);

        bf16x8 ahf[2], alf[2];
#pragma unroll
        for (int m = 0; m < 2; ++m) {
            const int row = m * 16 + cl;
            ahf[m] = *(const bf16x8*)&Ah[row][p * 8];
            alf[m] = *(const bf16x8*)&Al[row][p * 8];
        }
#pragma unroll
        for (int t = 0; t < 6; ++t) {
            const size_t bb = ((size_t)(c * NTILES + (w * 6 + t)) * 64 + lane) * 8;
            const bf16x8 bhf = *(const bf16x8*)(bh_g + bb);
            const bf16x8 blf = *(const bf16x8*)(bl_g + bb);
#pragma unroll
            for (int m = 0; m < 2; ++m) {
                acc[m][t] = __builtin_amdgcn_mfma_f32_16x16x32_bf16(ahf[m], bhf, acc[m][t], 0, 0, 0);
                acc[m][t] = __builtin_amdgcn_mfma_f32_16x16x32_bf16(ahf[m], blf, acc[m][t], 0, 0, 0);
                acc[m][t] = __builtin_amdgcn_mfma_f32_16x16x32_bf16(alf[m], bhf, acc[m][t], 0, 0, 0);
            }
        }
    }

    // ---- epilogue (identical to v6) ----
    float b1v[6], gv[6], bev[6], w2v[6];
#pragma unroll
    for (int t = 0; t < 6; ++t) {
        const int n = (w * 6 + t) * 16 + cl;
        b1v[t] = b1[n]; gv[t] = gamma[n]; bev[t] = beta[n]; w2v[t] = W2[n];
    }
#pragma unroll
    for (int m = 0; m < 2; ++m)
#pragma unroll
        for (int t = 0; t < 6; ++t)
#pragma unroll
            for (int r = 0; r < 4; ++r) acc[m][t][r] += b1v[t];

#pragma unroll
    for (int m = 0; m < 2; ++m) {
        float sm[4] = {0.f, 0.f, 0.f, 0.f};
#pragma unroll
        for (int t = 0; t < 6; ++t)
#pragma unroll
            for (int r = 0; r < 4; ++r) sm[r] += acc[m][t][r];
#pragma unroll
        for (int r = 0; r < 4; ++r) {
#pragma unroll
            for (int off = 1; off <= 8; off <<= 1) sm[r] += __shfl_xor(sm[r], off, 64);
        }
        if (cl == 0) {
#pragma unroll
            for (int r = 0; r < 4; ++r) red[w][m * 16 + p * 4 + r] = sm[r];
        }
    }
    __syncthreads();
    if (tid < 32) mu_s[tid] = (red[0][tid] + red[1][tid] + red[2][tid] + red[3][tid]) * (1.0f / H_);
    __syncthreads();

#pragma unroll
    for (int m = 0; m < 2; ++m) {
        float mur[4];
#pragma unroll
        for (int r = 0; r < 4; ++r) mur[r] = mu_s[m * 16 + p * 4 + r];
        float sm[4] = {0.f, 0.f, 0.f, 0.f};
#pragma unroll
        for (int t = 0; t < 6; ++t)
#pragma unroll
            for (int r = 0; r < 4; ++r) { const float d = acc[m][t][r] - mur[r]; sm[r] += d * d; }
#pragma unroll
        for (int r = 0; r < 4; ++r) {
#pragma unroll
            for (int off = 1; off <= 8; off <<= 1) sm[r] += __shfl_xor(sm[r], off, 64);
        }
        if (cl == 0) {
#pragma unroll
            for (int r = 0; r < 4; ++r) red[w][m * 16 + p * 4 + r] = sm[r];
        }
    }
    __syncthreads();
    if (tid < 32) rs_s[tid] = rsqrtf((red[0][tid] + red[1][tid] + red[2][tid] + red[3][tid]) * (1.0f / H_) + 1e-5f);
    __syncthreads();

#pragma unroll
    for (int m = 0; m < 2; ++m) {
        float mur[4], rsr[4];
#pragma unroll
        for (int r = 0; r < 4; ++r) { mur[r] = mu_s[m * 16 + p * 4 + r]; rsr[r] = rs_s[m * 16 + p * 4 + r]; }
        float sm[4] = {0.f, 0.f, 0.f, 0.f};
#pragma unroll
        for (int t = 0; t < 6; ++t)
#pragma unroll
            for (int r = 0; r < 4; ++r) {
                const float y  = (acc[m][t][r] - mur[r]) * rsr[r] * gv[t] + bev[t];
                const float ge = 0.5f * y * (1.0f + erff(y * 0.70710678118654752f));
                sm[r] = fmaf(ge, w2v[t], sm[r]);
            }
#pragma unroll
        for (int r = 0; r < 4; ++r) {
#pragma unroll
            for (int off = 1; off <= 8; off <<= 1) sm[r] += __shfl_xor(sm[r], off, 64);
        }
        if (cl == 0) {
#pragma unroll
            for (int r = 0; r < 4; ++r) red[w][m * 16 + p * 4 + r] = sm[r];
        }
    }
    __syncthreads();
    if (tid < 32) {
        const float s = red[0][tid] + red[1][tid] + red[2][tid] + red[3][tid] + b2[0];
        escore[b * NCAND + g * 32 + tid] = 1.0f / (1.0f + expf(-s));
    }
}

// ---------------------------------------------------------------------------
// Kernel 4: final exact top-40 among the 128 rescored candidates per batch.
// Rank by (score desc, index asc) — matches jax top_k tie semantics.
// ---------------------------------------------------------------------------
__global__ __launch_bounds__(NCAND) void final_kernel(const float* __restrict__ escore,
                                                      const int* __restrict__ cand,
                                                      int* __restrict__ sel)
{
    __shared__ float s_s[NCAND];
    __shared__ int   s_i[NCAND];
    const int b   = blockIdx.x;
    const int tid = threadIdx.x;

    s_s[tid] = escore[b * NCAND + tid];
    s_i[tid] = cand[b * NCAND + tid];
    __syncthreads();

    const float s = s_s[tid];
    const int   idx = s_i[tid];
    int rank = 0;
    for (int l = 0; l < NCAND; ++l)
        rank += (s_s[l] > s || (s_s[l] == s && s_i[l] < idx)) ? 1 : 0;
    if (rank < KTOP) sel[b * KTOP + rank] = idx;
}

// ---------------------------------------------------------------------------
// Kernel 5: gather selected rows + write indices (as float). Grid (40,16).
// ---------------------------------------------------------------------------
__global__ __launch_bounds__(192) void gather_kernel(const float* __restrict__ features,
                                                     const int* __restrict__ sel,
                                                     float* __restrict__ out_tok,
                                                     float* __restrict__ out_idx)
{
    const int i = blockIdx.x;   // 0..39
    const int b = blockIdx.y;   // 0..15
    const int idx = sel[b * KTOP + i];
    const float4* src = (const float4*)(features + ((size_t)b * S_ + idx) * D_);
    float4* dst = (float4*)(out_tok + ((size_t)b * KTOP + i) * D_);
    dst[threadIdx.x] = src[threadIdx.x];
    if (threadIdx.x == 0) out_idx[b * KTOP + i] = (float)idx;
}

// ---------------------------------------------------------------------------
extern "C" void kernel_launch(void* const* d_in, const int* in_sizes, int n_in,
                              void* d_out, int out_size, void* d_ws, size_t ws_size,
                              hipStream_t stream)
{
    const float* features = (const float*)d_in[0];
    const float* W1       = (const float*)d_in[1];
    const float* b1       = (const float*)d_in[2];
    const float* gamma    = (const float*)d_in[3];
    const float* beta     = (const float*)d_in[4];
    const float* W2       = (const float*)d_in[5];
    const float* b2       = (const float*)d_in[6];

    // ws layout
    unsigned short* bh = (unsigned short*)d_ws;              // 576 KB
    unsigned short* bl = bh + (size_t)D_ * H_;               // 576 KB
    float* scores      = (float*)(bl + (size_t)D_ * H_);     // 256 KB
    int*   cand        = (int*)(scores + NTOK);              // 8 KB
    float* escore      = (float*)(cand + B_ * NCAND);        // 8 KB
    int*   sel         = (int*)(escore + B_ * NCAND);        // 2.5 KB

    float* out        = (float*)d_out;
    float* out_tokens = out;                                 // [16,40,768]
    float* out_idx    = out + (size_t)B_ * KTOP * D_;        // [16,40]

    pack_w1<<<dim3(NTILES, KCH), 64, 0, stream>>>(W1, bh, bl);
    score_kernel<<<NTOK / 64, 256, 0, stream>>>(features, bh, b1, gamma, beta, W2, b2, scores);
    cand_kernel<<<B_, 256, 0, stream>>>(scores, cand);
    rescore_kernel<<<dim3(NCAND / 32, B_), 256, 0, stream>>>(
        features, bh, bl, b1, gamma, beta, W2, b2, cand, escore);
    final_kernel<<<B_, NCAND, 0, stream>>>(escore, cand, sel);
    gather_kernel<<<dim3(KTOP, B_), 192, 0, stream>>>(features, sel, out_tokens, out_idx);
}

// Round 10
// 509.445 us; speedup vs baseline: 1.2640x; 1.2640x over previous
//
#include <hip/hip_runtime.h>
#include <hip/hip_bf16.h>
#include <math.h>

#define B_   16
#define S_   4096
#define D_   768
#define H_   384
#define NTOK (B_ * S_)
#define KTOP 40
#define NCAND 128          // filter keeps top-128 per batch; true top-40 margin ~100x
#define NTILES 24          // 384/16 n-tiles
#define KCH    24          // 768/32 k-chunks

typedef __attribute__((ext_vector_type(8))) short bf16x8;
typedef __attribute__((ext_vector_type(4))) float f32x4;

static __device__ __forceinline__ unsigned short f2bf(float x) {
    __hip_bfloat16 h = __float2bfloat16(x);   // HW RNE convert
    unsigned short r;
    __builtin_memcpy(&r, &h, sizeof(r));
    return r;
}
static __device__ __forceinline__ float bf2f(unsigned short h) {
    union { unsigned u; float f; } v; v.u = ((unsigned)h) << 16; return v.f;
}

// Raw workgroup barrier WITHOUT the vmcnt(0) drain __syncthreads() emits.
#define KBARRIER()                                                \
    do {                                                          \
        asm volatile("s_waitcnt lgkmcnt(0)" ::: "memory");        \
        __builtin_amdgcn_s_barrier();                             \
        asm volatile("" ::: "memory");                            \
    } while (0)

// ---------------------------------------------------------------------------
// Kernel 0: pack W1 (fp32 [768][384]) into CHUNK-MAJOR MFMA B layout, bf16
// hi/lo. Fragment element j of lane:
//   B[k = ch*32 + (lane>>4)*8 + j][n = nt*16 + (lane&15)]
//   dst = ((ch*NTILES + nt)*64 + lane)*8
// ---------------------------------------------------------------------------
__global__ __launch_bounds__(64) void pack_w1(const float* __restrict__ W1,
                                              unsigned short* __restrict__ bh,
                                              unsigned short* __restrict__ bl)
{
    const int nt   = blockIdx.x;        // 0..23
    const int ch   = blockIdx.y;        // 0..23
    const int lane = threadIdx.x;
    const int n    = nt * 16 + (lane & 15);
    const int k0   = ch * 32 + (lane >> 4) * 8;

    const size_t dst = ((size_t)(ch * NTILES + nt) * 64 + lane) * 8;
#pragma unroll
    for (int j = 0; j < 8; ++j) {
        const float v = W1[(size_t)(k0 + j) * H_ + n];
        const unsigned short h = f2bf(v);
        bh[dst + j] = h;
        bl[dst + j] = f2bf(v - bf2f(h));
    }
}

// ---------------------------------------------------------------------------
// Kernel 1: APPROXIMATE filter scores — barrier-free k-loop, SPILL-FIXED.
// v8 spilled: acc[24] (96 VGPR) + 24 hoisted B-frags (96 VGPR) > the
// launch_bounds(256,3) cap of ~170 -> scratch (VGPR=84, WRITE 175MB).
// v9 halves the per-wave tile: wave w owns row-group g=w>>1 (16 rows) x
// col-half h=w&1 (12 n-tiles). acc[12]=48 VGPR + <=48 B-frags + ~35 misc
// ~= 130 live, fits. K-loop has NO LDS and NO barriers; the LN reduction
// combines the two col-half waves via 256B LDS at the EPILOGUE only.
// Block = 32 rows (4 waves), grid 2048. B chunk-major (24KB hot slice).
// ---------------------------------------------------------------------------
__global__ __launch_bounds__(256, 3) void score_kernel(
    const float* __restrict__ features,
    const unsigned short* __restrict__ bh_g,
    const float* __restrict__ b1,
    const float* __restrict__ gamma,
    const float* __restrict__ beta,
    const float* __restrict__ W2,
    const float* __restrict__ b2,
    float* __restrict__ scores)
{
    __shared__ float red[4][16];        // per-wave 16 row-partials

    const int tid  = threadIdx.x;
    const int lane = tid & 63;
    const int w    = tid >> 6;
    const int h    = w & 1;             // col half: n-tiles h*12..h*12+11
    const int g    = w >> 1;            // row group
    const int cl   = lane & 15;
    const int p    = lane >> 4;
    const int rowbase = blockIdx.x * 32 + g * 16;

    f32x4 acc[12];
#pragma unroll
    for (int t = 0; t < 12; ++t) acc[t] = (f32x4){0.f, 0.f, 0.f, 0.f};

    // lane's own A-fragment source: row rowbase+cl, cols p*8..p*8+7
    const float* arow = features + (size_t)(rowbase + cl) * D_ + p * 8;

    float4 a0 = *(const float4*)(arow);
    float4 a1 = *(const float4*)(arow + 4);

    for (int c = 0; c < KCH; ++c) {
        float4 n0, n1;
        if (c + 1 < KCH) {
            n0 = *(const float4*)(arow + (c + 1) * 32);
            n1 = *(const float4*)(arow + (c + 1) * 32 + 4);
        }
        bf16x8 ah;
        ah[0] = (short)f2bf(a0.x); ah[1] = (short)f2bf(a0.y);
        ah[2] = (short)f2bf(a0.z); ah[3] = (short)f2bf(a0.w);
        ah[4] = (short)f2bf(a1.x); ah[5] = (short)f2bf(a1.y);
        ah[6] = (short)f2bf(a1.z); ah[7] = (short)f2bf(a1.w);

        // 12 independent MFMA chains; this wave's B slice = 12KB of the
        // chunk's 24KB hot region
        const unsigned short* bb =
            bh_g + ((size_t)c * NTILES + h * 12) * (64 * 8) + lane * 8;
#pragma unroll
        for (int t = 0; t < 12; ++t) {
            const bf16x8 bf = *(const bf16x8*)(bb + t * (64 * 8));
            acc[t] = __builtin_amdgcn_mfma_f32_16x16x32_bf16(ah, bf, acc[t], 0, 0, 0);
        }
        if (c + 1 < KCH) { a0 = n0; a1 = n1; }
    }

    // ---- epilogue: rows p*4+r, cols (h*12+t)*16+cl ----
#pragma unroll
    for (int t = 0; t < 12; ++t) {
        const float bv = b1[(h * 12 + t) * 16 + cl];
#pragma unroll
        for (int r = 0; r < 4; ++r) acc[t][r] += bv;
    }
    // mean: wave-local partial, then 2-wave combine via LDS
    float mu[4];
    {
        float sm[4] = {0.f, 0.f, 0.f, 0.f};
#pragma unroll
        for (int t = 0; t < 12; ++t)
#pragma unroll
            for (int r = 0; r < 4; ++r) sm[r] += acc[t][r];
#pragma unroll
        for (int r = 0; r < 4; ++r) {
#pragma unroll
            for (int off = 1; off <= 8; off <<= 1) sm[r] += __shfl_xor(sm[r], off, 64);
        }
        if (cl == 0) {
#pragma unroll
            for (int r = 0; r < 4; ++r) red[w][p * 4 + r] = sm[r];
        }
        __syncthreads();
#pragma unroll
        for (int r = 0; r < 4; ++r)
            mu[r] = (red[g * 2][p * 4 + r] + red[g * 2 + 1][p * 4 + r]) * (1.0f / H_);
        __syncthreads();
    }
    // variance
    float rs[4];
    {
        float sv[4] = {0.f, 0.f, 0.f, 0.f};
#pragma unroll
        for (int t = 0; t < 12; ++t)
#pragma unroll
            for (int r = 0; r < 4; ++r) { const float d = acc[t][r] - mu[r]; sv[r] += d * d; }
#pragma unroll
        for (int r = 0; r < 4; ++r) {
#pragma unroll
            for (int off = 1; off <= 8; off <<= 1) sv[r] += __shfl_xor(sv[r], off, 64);
        }
        if (cl == 0) {
#pragma unroll
            for (int r = 0; r < 4; ++r) red[w][p * 4 + r] = sv[r];
        }
        __syncthreads();
#pragma unroll
        for (int r = 0; r < 4; ++r)
            rs[r] = rsqrtf((red[g * 2][p * 4 + r] + red[g * 2 + 1][p * 4 + r]) * (1.0f / H_) + 1e-5f);
        __syncthreads();
    }
    // LN + gelu + W2 dot
    {
        float ss[4] = {0.f, 0.f, 0.f, 0.f};
#pragma unroll
        for (int t = 0; t < 12; ++t) {
            const int n = (h * 12 + t) * 16 + cl;
            const float gv = gamma[n], bev = beta[n], wv = W2[n];
#pragma unroll
            for (int r = 0; r < 4; ++r) {
                const float y  = (acc[t][r] - mu[r]) * rs[r] * gv + bev;
                const float ge = 0.5f * y * (1.0f + erff(y * 0.70710678118654752f));
                ss[r] = fmaf(ge, wv, ss[r]);
            }
        }
#pragma unroll
        for (int r = 0; r < 4; ++r) {
#pragma unroll
            for (int off = 1; off <= 8; off <<= 1) ss[r] += __shfl_xor(ss[r], off, 64);
        }
        if (cl == 0) {
#pragma unroll
            for (int r = 0; r < 4; ++r) red[w][p * 4 + r] = ss[r];
        }
        __syncthreads();
        if (h == 0 && cl == 0) {
#pragma unroll
            for (int r = 0; r < 4; ++r) {
                const float s = red[g * 2][p * 4 + r] + red[g * 2 + 1][p * 4 + r] + b2[0];
                scores[rowbase + p * 4 + r] = 1.0f / (1.0f + expf(-s));
            }
        }
    }
}

// ---------------------------------------------------------------------------
// Kernel 2: per-batch top-NCAND(128) candidates via byte-wise radix select on
// approx score bits (scores > 0 so uint order == float order). Ties -> lower
// index. Output order irrelevant: final kernel re-sorts by exact score.
// ---------------------------------------------------------------------------
__global__ __launch_bounds__(256) void cand_kernel(const float* __restrict__ scores,
                                                   int* __restrict__ cand)
{
    __shared__ unsigned int bits_s[S_];     // 16 KB
    __shared__ unsigned int hist[256];
    __shared__ unsigned int suf[256];
    __shared__ unsigned int wtot[4];
    __shared__ int s_byte, s_rem;
    __shared__ unsigned int s_ngt, s_neq;
    __shared__ unsigned int candV[NCAND];
    __shared__ int candI[NCAND];
    __shared__ int eqI[256];

    const int b    = blockIdx.x;
    const int tid  = threadIdx.x;
    const int lane = tid & 63;
    const int w4   = tid >> 6;

    for (int i = tid; i < S_; i += 256)
        bits_s[i] = __float_as_uint(scores[b * S_ + i]);
    if (tid == 0) { s_rem = NCAND; s_ngt = 0u; s_neq = 0u; }

    unsigned int prefix = 0u, mask = 0u;
    for (int pb = 3; pb >= 0; --pb) {
        hist[tid] = 0u;
        __syncthreads();
        for (int i = tid; i < S_; i += 256) {
            const unsigned int u = bits_s[i];
            if ((u & mask) == prefix) atomicAdd(&hist[(u >> (8 * pb)) & 255u], 1u);
        }
        __syncthreads();
        {
            unsigned int v = hist[tid];
#pragma unroll
            for (int off = 1; off < 64; off <<= 1) {
                const unsigned int y = __shfl_down(v, off, 64);
                if (lane + off < 64) v += y;
            }
            if (lane == 0) wtot[w4] = v;
            __syncthreads();
            unsigned int add = 0u;
#pragma unroll
            for (int j = 0; j < 4; ++j) if (j > w4) add += wtot[j];
            v += add;
            suf[tid] = v;
            __syncthreads();
            const int rem = s_rem;
            const unsigned int nxt = (tid < 255) ? suf[tid + 1] : 0u;
            if (suf[tid] >= (unsigned)rem && (tid == 255 || nxt < (unsigned)rem)) {
                s_byte = tid;
                s_rem  = rem - (int)nxt;
            }
        }
        __syncthreads();
        prefix |= ((unsigned int)s_byte) << (8 * pb);
        mask   |= 0xFFu << (8 * pb);
        __syncthreads();
    }
    const unsigned int T = prefix;
    const int need = s_rem;                 // 1..: #ties at T to keep

    for (int i = tid; i < S_; i += 256) {
        const unsigned int u = bits_s[i];
        if (u > T) {
            const unsigned int pos = atomicAdd(&s_ngt, 1u);
            candV[pos] = u; candI[pos] = i;          // n_gt <= NCAND-1 guaranteed
        } else if (u == T) {
            const unsigned int pos = atomicAdd(&s_neq, 1u);
            if (pos < 256u) eqI[pos] = i;
        }
    }
    __syncthreads();
    const int ngt = (int)s_ngt;
    const int neq = (int)(s_neq < 256u ? s_neq : 256u);
    for (int j = tid; j < neq; j += 256) {
        int rank = 0;
        for (int l = 0; l < neq; ++l) rank += (eqI[l] < eqI[j]) ? 1 : 0;
        if (rank < need) { candV[ngt + rank] = T; candI[ngt + rank] = eqI[j]; }
    }
    __syncthreads();
    if (tid < NCAND) cand[b * NCAND + tid] = candI[tid];
}

// ---------------------------------------------------------------------------
// Kernel 3: EXACT rescore = the proven v6 3-term bf16-split MFMA kernel
// applied to 32 candidates per block (grid 4 x 16). Per-token arithmetic and
// accumulation order IDENTICAL to v6 (absmax 0, three times now).
// ---------------------------------------------------------------------------
__global__ __launch_bounds__(256, 4) void rescore_kernel(
    const float* __restrict__ features,
    const unsigned short* __restrict__ bh_g,
    const unsigned short* __restrict__ bl_g,
    const float* __restrict__ b1,
    const float* __restrict__ gamma,
    const float* __restrict__ beta,
    const float* __restrict__ W2,
    const float* __restrict__ b2,
    const int* __restrict__ cand,
    float* __restrict__ escore)
{
    __shared__ unsigned short Ah[32][40];
    __shared__ unsigned short Al[32][40];
    __shared__ float red[4][32];
    __shared__ float mu_s[32];
    __shared__ float rs_s[32];

    const int tid  = threadIdx.x;
    const int lane = tid & 63;
    const int w    = tid >> 6;
    const int g    = blockIdx.x;            // candidate group 0..3
    const int b    = blockIdx.y;            // batch 0..15
    const int cl   = lane & 15;
    const int p    = lane >> 4;

    f32x4 acc[2][6];
#pragma unroll
    for (int m = 0; m < 2; ++m)
#pragma unroll
        for (int t = 0; t < 6; ++t) acc[m][t] = (f32x4){0.f, 0.f, 0.f, 0.f};

    const int r0 = tid >> 3, c0 = (tid & 7) * 4;
    const int ci = cand[b * NCAND + g * 32 + r0];
    const float* arow = features + ((size_t)b * S_ + ci) * D_ + c0;

    float4 p0 = *(const float4*)(arow);

    for (int c = 0; c < KCH; ++c) {
        if (c) KBARRIER();
        {
            unsigned short h0 = f2bf(p0.x), h1 = f2bf(p0.y), h2 = f2bf(p0.z), h3 = f2bf(p0.w);
            Ah[r0][c0] = h0; Ah[r0][c0+1] = h1; Ah[r0][c0+2] = h2; Ah[r0][c0+3] = h3;
            Al[r0][c0]   = f2bf(p0.x - bf2f(h0));
            Al[r0][c0+1] = f2bf(p0.y - bf2f(h1));
            Al[r0][c0+2] = f2bf(p0.z - bf2f(h2));
            Al[r0][c0+3] = f2bf(p0.w - bf2f(h3));
        }
        KBARRIER();

        if (c + 1 < KCH) p0 = *(const float4*)(arow + (c + 1) * 32);

        bf16x8 ahf[2], alf[2];
#pragma unroll
        for (int m = 0; m < 2; ++m) {
            const int row = m * 16 + cl;
            ahf[m] = *(const bf16x8*)&Ah[row][p * 8];
            alf[m] = *(const bf16x8*)&Al[row][p * 8];
        }
#pragma unroll
        for (int t = 0; t < 6; ++t) {
            const size_t bb = ((size_t)(c * NTILES + (w * 6 + t)) * 64 + lane) * 8;
            const bf16x8 bhf = *(const bf16x8*)(bh_g + bb);
            const bf16x8 blf = *(const bf16x8*)(bl_g + bb);
#pragma unroll
            for (int m = 0; m < 2; ++m) {
                acc[m][t] = __builtin_amdgcn_mfma_f32_16x16x32_bf16(ahf[m], bhf, acc[m][t], 0, 0, 0);
                acc[m][t] = __builtin_amdgcn_mfma_f32_16x16x32_bf16(ahf[m], blf, acc[m][t], 0, 0, 0);
                acc[m][t] = __builtin_amdgcn_mfma_f32_16x16x32_bf16(alf[m], bhf, acc[m][t], 0, 0, 0);
            }
        }
    }

    // ---- epilogue (identical to v6) ----
    float b1v[6], gv[6], bev[6], w2v[6];
#pragma unroll
    for (int t = 0; t < 6; ++t) {
        const int n = (w * 6 + t) * 16 + cl;
        b1v[t] = b1[n]; gv[t] = gamma[n]; bev[t] = beta[n]; w2v[t] = W2[n];
    }
#pragma unroll
    for (int m = 0; m < 2; ++m)
#pragma unroll
        for (int t = 0; t < 6; ++t)
#pragma unroll
            for (int r = 0; r < 4; ++r) acc[m][t][r] += b1v[t];

#pragma unroll
    for (int m = 0; m < 2; ++m) {
        float sm[4] = {0.f, 0.f, 0.f, 0.f};
#pragma unroll
        for (int t = 0; t < 6; ++t)
#pragma unroll
            for (int r = 0; r < 4; ++r) sm[r] += acc[m][t][r];
#pragma unroll
        for (int r = 0; r < 4; ++r) {
#pragma unroll
            for (int off = 1; off <= 8; off <<= 1) sm[r] += __shfl_xor(sm[r], off, 64);
        }
        if (cl == 0) {
#pragma unroll
            for (int r = 0; r < 4; ++r) red[w][m * 16 + p * 4 + r] = sm[r];
        }
    }
    __syncthreads();
    if (tid < 32) mu_s[tid] = (red[0][tid] + red[1][tid] + red[2][tid] + red[3][tid]) * (1.0f / H_);
    __syncthreads();

#pragma unroll
    for (int m = 0; m < 2; ++m) {
        float mur[4];
#pragma unroll
        for (int r = 0; r < 4; ++r) mur[r] = mu_s[m * 16 + p * 4 + r];
        float sm[4] = {0.f, 0.f, 0.f, 0.f};
#pragma unroll
        for (int t = 0; t < 6; ++t)
#pragma unroll
            for (int r = 0; r < 4; ++r) { const float d = acc[m][t][r] - mur[r]; sm[r] += d * d; }
#pragma unroll
        for (int r = 0; r < 4; ++r) {
#pragma unroll
            for (int off = 1; off <= 8; off <<= 1) sm[r] += __shfl_xor(sm[r], off, 64);
        }
        if (cl == 0) {
#pragma unroll
            for (int r = 0; r < 4; ++r) red[w][m * 16 + p * 4 + r] = sm[r];
        }
    }
    __syncthreads();
    if (tid < 32) rs_s[tid] = rsqrtf((red[0][tid] + red[1][tid] + red[2][tid] + red[3][tid]) * (1.0f / H_) + 1e-5f);
    __syncthreads();

#pragma unroll
    for (int m = 0; m < 2; ++m) {
        float mur[4], rsr[4];
#pragma unroll
        for (int r = 0; r < 4; ++r) { mur[r] = mu_s[m * 16 + p * 4 + r]; rsr[r] = rs_s[m * 16 + p * 4 + r]; }
        float sm[4] = {0.f, 0.f, 0.f, 0.f};
#pragma unroll
        for (int t = 0; t < 6; ++t)
#pragma unroll
            for (int r = 0; r < 4; ++r) {
                const float y  = (acc[m][t][r] - mur[r]) * rsr[r] * gv[t] + bev[t];
                const float ge = 0.5f * y * (1.0f + erff(y * 0.70710678118654752f));
                sm[r] = fmaf(ge, w2v[t], sm[r]);
            }
#pragma unroll
        for (int r = 0; r < 4; ++r) {
#pragma unroll
            for (int off = 1; off <= 8; off <<= 1) sm[r] += __shfl_xor(sm[r], off, 64);
        }
        if (cl == 0) {
#pragma unroll
            for (int r = 0; r < 4; ++r) red[w][m * 16 + p * 4 + r] = sm[r];
        }
    }
    __syncthreads();
    if (tid < 32) {
        const float s = red[0][tid] + red[1][tid] + red[2][tid] + red[3][tid] + b2[0];
        escore[b * NCAND + g * 32 + tid] = 1.0f / (1.0f + expf(-s));
    }
}

// ---------------------------------------------------------------------------
// Kernel 4: final exact top-40 among the 128 rescored candidates per batch.
// Rank by (score desc, index asc) — matches jax top_k tie semantics.
// ---------------------------------------------------------------------------
__global__ __launch_bounds__(NCAND) void final_kernel(const float* __restrict__ escore,
                                                      const int* __restrict__ cand,
                                                      int* __restrict__ sel)
{
    __shared__ float s_s[NCAND];
    __shared__ int   s_i[NCAND];
    const int b   = blockIdx.x;
    const int tid = threadIdx.x;

    s_s[tid] = escore[b * NCAND + tid];
    s_i[tid] = cand[b * NCAND + tid];
    __syncthreads();

    const float s = s_s[tid];
    const int   idx = s_i[tid];
    int rank = 0;
    for (int l = 0; l < NCAND; ++l)
        rank += (s_s[l] > s || (s_s[l] == s && s_i[l] < idx)) ? 1 : 0;
    if (rank < KTOP) sel[b * KTOP + rank] = idx;
}

// ---------------------------------------------------------------------------
// Kernel 5: gather selected rows + write indices (as float). Grid (40,16).
// ---------------------------------------------------------------------------
__global__ __launch_bounds__(192) void gather_kernel(const float* __restrict__ features,
                                                     const int* __restrict__ sel,
                                                     float* __restrict__ out_tok,
                                                     float* __restrict__ out_idx)
{
    const int i = blockIdx.x;   // 0..39
    const int b = blockIdx.y;   // 0..15
    const int idx = sel[b * KTOP + i];
    const float4* src = (const float4*)(features + ((size_t)b * S_ + idx) * D_);
    float4* dst = (float4*)(out_tok + ((size_t)b * KTOP + i) * D_);
    dst[threadIdx.x] = src[threadIdx.x];
    if (threadIdx.x == 0) out_idx[b * KTOP + i] = (float)idx;
}

// ---------------------------------------------------------------------------
extern "C" void kernel_launch(void* const* d_in, const int* in_sizes, int n_in,
                              void* d_out, int out_size, void* d_ws, size_t ws_size,
                              hipStream_t stream)
{
    const float* features = (const float*)d_in[0];
    const float* W1       = (const float*)d_in[1];
    const float* b1       = (const float*)d_in[2];
    const float* gamma    = (const float*)d_in[3];
    const float* beta     = (const float*)d_in[4];
    const float* W2       = (const float*)d_in[5];
    const float* b2       = (const float*)d_in[6];

    // ws layout
    unsigned short* bh = (unsigned short*)d_ws;              // 576 KB
    unsigned short* bl = bh + (size_t)D_ * H_;               // 576 KB
    float* scores      = (float*)(bl + (size_t)D_ * H_);     // 256 KB
    int*   cand        = (int*)(scores + NTOK);              // 8 KB
    float* escore      = (float*)(cand + B_ * NCAND);        // 8 KB
    int*   sel         = (int*)(escore + B_ * NCAND);        // 2.5 KB

    float* out        = (float*)d_out;
    float* out_tokens = out;                                 // [16,40,768]
    float* out_idx    = out + (size_t)B_ * KTOP * D_;        // [16,40]

    pack_w1<<<dim3(NTILES, KCH), 64, 0, stream>>>(W1, bh, bl);
    score_kernel<<<NTOK / 32, 256, 0, stream>>>(features, bh, b1, gamma, beta, W2, b2, scores);
    cand_kernel<<<B_, 256, 0, stream>>>(scores, cand);
    rescore_kernel<<<dim3(NCAND / 32, B_), 256, 0, stream>>>(
        features, bh, bl, b1, gamma, beta, W2, b2, cand, escore);
    final_kernel<<<B_, NCAND, 0, stream>>>(escore, cand, sel);
    gather_kernel<<<dim3(KTOP, B_), 192, 0, stream>>>(features, sel, out_tokens, out_idx);
}